// Round 1
// baseline (239.706 us; speedup 1.0000x reference)
//
#include <hip/hip_runtime.h>

#define LOG2E 1.4426950408889634f

typedef float f32x4 __attribute__((ext_vector_type(4)));
typedef short s16x8 __attribute__((ext_vector_type(8)));
typedef __bf16 bf16x8 __attribute__((ext_vector_type(8)));

union ABF { s16x8 s; bf16x8 v; };

__device__ __forceinline__ unsigned short f2bf(float f) {
  unsigned int u = __builtin_bit_cast(unsigned int, f);
  u += 0x7fffu + ((u >> 16) & 1u);
  return (unsigned short)(u >> 16);
}

// ---------------- prep kernels ----------------

__global__ __launch_bounds__(256) void k_cvt_bf16(const float* __restrict__ src,
                                                  unsigned short* __restrict__ dst, int n) {
  int i = blockIdx.x * 256 + threadIdx.x;
  if (i < n) dst[i] = f2bf(src[i]);
}

// w4t[co][k], k = (dh*2+dw)*256 + ci ; from sr_w[co][ci][dh][dw]
__global__ __launch_bounds__(256) void k_repack_w4(const float* __restrict__ sr_w,
                                                   unsigned short* __restrict__ w4t) {
  int idx = blockIdx.x * 256 + threadIdx.x;  // 256*1024
  int co = idx >> 10, k = idx & 1023;
  int slot = k >> 8, ci = k & 255;
  int dh = slot >> 1, dw = slot & 1;
  w4t[idx] = f2bf(sr_w[((co * 256 + ci) * 2 + dh) * 2 + dw]);
}

// token2map gather, rearranged for conv-as-GEMM:
// x4[b*1024 + (y>>1)*32+(x>>1)][((y&1)*2+(x&1))*256 + c] = kv_x[b, idx, c]/1.000001
__global__ __launch_bounds__(256) void k_gather_x4(const float* __restrict__ kv_x,
                                                   const int* __restrict__ idx_token,
                                                   unsigned short* __restrict__ x4) {
  int b = blockIdx.y, i = blockIdx.x, c = threadIdx.x;
  int tok = idx_token[b * 4096 + i];
  int y = i >> 6, x = i & 63;
  int row = ((y >> 1) << 5) + (x >> 1);
  int slot = ((y & 1) << 1) + (x & 1);
  const float inv1 = 1.0f / 1.000001f;
  x4[(size_t)((b * 1024 + row) * 4 + slot) * 256 + c] =
      f2bf(kv_x[(size_t)(b * 2048 + tok) * 256 + c] * inv1);
}

// conf[b][m] = log2e * mean_{2x2}(token_score gathered) / 1.000001
__global__ __launch_bounds__(256) void k_conf(const float* __restrict__ token_score,
                                              const int* __restrict__ idx_token,
                                              float* __restrict__ conf) {
  int t = blockIdx.x * 256 + threadIdx.x;  // B*1024
  int b = t >> 10, m = t & 1023;
  int h = m >> 5, w = m & 31;
  float s = 0.f;
#pragma unroll
  for (int dh = 0; dh < 2; ++dh)
#pragma unroll
    for (int dw = 0; dw < 2; ++dw) {
      int i = (2 * h + dh) * 64 + (2 * w + dw);
      s += token_score[b * 2048 + idx_token[b * 4096 + i]];
    }
  conf[t] = s * 0.25f * (1.0f / 1.000001f) * LOG2E;
}

// ---------------- GEMM kernels (16 rows x block, 4 waves) ----------------

// q_s[(b*8+h)*2048 + n][d] = bf16( (q_x @ q_w^T) * SCALE * LOG2E )
__global__ __launch_bounds__(256) void k_qproj(const unsigned short* __restrict__ xa,
                                               const unsigned short* __restrict__ wb,
                                               unsigned short* __restrict__ q_s) {
  int tid = threadIdx.x;
  int wid = tid >> 6, lane = tid & 63, lg = lane >> 4, lc = lane & 15;
  int rowbase = blockIdx.x * 16;
  f32x4 acc[4] = {};
  const unsigned short* ap = xa + (size_t)(rowbase + lc) * 256 + lg * 8;
#pragma unroll
  for (int kc = 0; kc < 8; ++kc) {
    ABF a; a.s = *(const s16x8*)(ap + kc * 32);
#pragma unroll
    for (int t = 0; t < 4; ++t) {
      ABF bb; bb.s = *(const s16x8*)(wb + (size_t)(wid * 64 + t * 16 + lc) * 256 + kc * 32 + lg * 8);
      acc[t] = __builtin_amdgcn_mfma_f32_16x16x32_bf16(a.v, bb.v, acc[t], 0, 0, 0);
    }
  }
  const float qs = 0.17677669529663687f * LOG2E;
#pragma unroll
  for (int t = 0; t < 4; ++t) {
    int col = wid * 64 + t * 16 + lc;
    int h = col >> 5, d = col & 31;
#pragma unroll
    for (int r = 0; r < 4; ++r) {
      int row = rowbase + lg * 4 + r;
      int b = row >> 11, n = row & 2047;
      q_s[(size_t)((b * 8 + h) * 2048 + n) * 32 + d] = f2bf(acc[t][r] * qs);
    }
  }
}

// conv-as-GEMM (8192x256, K=1024) + bias + LayerNorm fused -> kv_ln bf16
__global__ __launch_bounds__(256) void k_conv_ln(const unsigned short* __restrict__ x4,
                                                 const unsigned short* __restrict__ w4t,
                                                 const float* __restrict__ sr_b,
                                                 const float* __restrict__ ln_w,
                                                 const float* __restrict__ ln_b,
                                                 unsigned short* __restrict__ kv_ln) {
  __shared__ float srow[16][260];
  int tid = threadIdx.x;
  int wid = tid >> 6, lane = tid & 63, lg = lane >> 4, lc = lane & 15;
  int rowbase = blockIdx.x * 16;
  f32x4 acc[4] = {};
  const unsigned short* ap = x4 + (size_t)(rowbase + lc) * 1024 + lg * 8;
  for (int kc = 0; kc < 32; ++kc) {
    ABF a; a.s = *(const s16x8*)(ap + kc * 32);
#pragma unroll
    for (int t = 0; t < 4; ++t) {
      ABF bb; bb.s = *(const s16x8*)(w4t + (size_t)(wid * 64 + t * 16 + lc) * 1024 + kc * 32 + lg * 8);
      acc[t] = __builtin_amdgcn_mfma_f32_16x16x32_bf16(a.v, bb.v, acc[t], 0, 0, 0);
    }
  }
#pragma unroll
  for (int t = 0; t < 4; ++t) {
    int col = wid * 64 + t * 16 + lc;
    float bias = sr_b[col];
#pragma unroll
    for (int r = 0; r < 4; ++r) srow[lg * 4 + r][col] = acc[t][r] + bias;
  }
  __syncthreads();
  int r = tid >> 4, c16 = tid & 15;
  float vals[16];
  float s = 0.f, ss = 0.f;
#pragma unroll
  for (int i = 0; i < 16; ++i) {
    float v = srow[r][c16 * 16 + i];
    vals[i] = v; s += v; ss += v * v;
  }
#pragma unroll
  for (int m = 1; m < 16; m <<= 1) {
    s += __shfl_xor(s, m, 64);
    ss += __shfl_xor(ss, m, 64);
  }
  float mu = s * (1.0f / 256.0f);
  float var = ss * (1.0f / 256.0f) - mu * mu;
  float rstd = rsqrtf(var + 1e-5f);
  s16x8 o0, o1;
#pragma unroll
  for (int i = 0; i < 8; ++i) {
    int c = c16 * 16 + i;
    o0[i] = (short)f2bf((vals[i] - mu) * rstd * ln_w[c] + ln_b[c]);
  }
#pragma unroll
  for (int i = 0; i < 8; ++i) {
    int c = c16 * 16 + 8 + i;
    o1[i] = (short)f2bf((vals[8 + i] - mu) * rstd * ln_w[c] + ln_b[c]);
  }
  *(s16x8*)(kv_ln + (size_t)(rowbase + r) * 256 + c16 * 16) = o0;
  *(s16x8*)(kv_ln + (size_t)(rowbase + r) * 256 + c16 * 16 + 8) = o1;
}

// kv projection (8192x512, K=256): col j = s*256 + h*32 + d; s==0 -> K[bh][m][d], s==1 -> Vt[bh][d][m]
__global__ __launch_bounds__(256) void k_kvproj(const unsigned short* __restrict__ kv_ln,
                                                const unsigned short* __restrict__ wb,
                                                unsigned short* __restrict__ kmat,
                                                unsigned short* __restrict__ vt) {
  int tid = threadIdx.x;
  int wid = tid >> 6, lane = tid & 63, lg = lane >> 4, lc = lane & 15;
  int rowbase = blockIdx.x * 16;
  f32x4 acc[8] = {};
  const unsigned short* ap = kv_ln + (size_t)(rowbase + lc) * 256 + lg * 8;
#pragma unroll
  for (int kc = 0; kc < 8; ++kc) {
    ABF a; a.s = *(const s16x8*)(ap + kc * 32);
#pragma unroll
    for (int t = 0; t < 8; ++t) {
      ABF bb; bb.s = *(const s16x8*)(wb + (size_t)(wid * 128 + t * 16 + lc) * 256 + kc * 32 + lg * 8);
      acc[t] = __builtin_amdgcn_mfma_f32_16x16x32_bf16(a.v, bb.v, acc[t], 0, 0, 0);
    }
  }
#pragma unroll
  for (int t = 0; t < 8; ++t) {
    int j = wid * 128 + t * 16 + lc;
    int sflag = j >> 8, h = (j >> 5) & 7, d = j & 31;
#pragma unroll
    for (int r = 0; r < 4; ++r) {
      int row = rowbase + lg * 4 + r;
      int b = row >> 10, m = row & 1023;
      unsigned short v = f2bf(acc[t][r]);
      if (sflag == 0) kmat[(size_t)((b * 8 + h) * 1024 + m) * 32 + d] = v;
      else            vt[(size_t)((b * 8 + h) * 32 + d) * 1024 + m] = v;
    }
  }
}

// ---------------- flash attention ----------------
// grid (32 qtiles, 64 bh), 4 waves x 16 q-rows. Logits in log2 domain.
__global__ __launch_bounds__(256) void k_attn(const unsigned short* __restrict__ q_s,
                                              const unsigned short* __restrict__ kmat,
                                              const unsigned short* __restrict__ vt,
                                              const float* __restrict__ conf,
                                              unsigned short* __restrict__ xat) {
  __shared__ unsigned short p_lds[4][16][72];
  int tid = threadIdx.x;
  int wid = tid >> 6, lane = tid & 63, lg = lane >> 4, lc = lane & 15;
  int bh = blockIdx.y, b = bh >> 3, h = bh & 7;
  int qbase = blockIdx.x * 64 + wid * 16;

  ABF qf; qf.s = *(const s16x8*)(q_s + (size_t)(bh * 2048 + qbase + lc) * 32 + lg * 8);
  f32x4 oacc0 = {}, oacc1 = {};
  float mrow[4] = {-1e30f, -1e30f, -1e30f, -1e30f};
  float lrow[4] = {0.f, 0.f, 0.f, 0.f};
  const float* cfp = conf + b * 1024;
  const unsigned short* kp = kmat + (size_t)bh * 1024 * 32;
  const unsigned short* vp = vt + (size_t)bh * 32 * 1024;

  for (int kb = 0; kb < 1024; kb += 64) {
    f32x4 s[4];
#pragma unroll
    for (int t = 0; t < 4; ++t) {
      float cf = cfp[kb + t * 16 + lc];
      ABF kf; kf.s = *(const s16x8*)(kp + (size_t)(kb + t * 16 + lc) * 32 + lg * 8);
      f32x4 cini = {cf, cf, cf, cf};
      s[t] = __builtin_amdgcn_mfma_f32_16x16x32_bf16(qf.v, kf.v, cini, 0, 0, 0);
    }
#pragma unroll
    for (int r = 0; r < 4; ++r) {
      float mx = fmaxf(fmaxf(s[0][r], s[1][r]), fmaxf(s[2][r], s[3][r]));
      mx = fmaxf(mx, __shfl_xor(mx, 1, 64));
      mx = fmaxf(mx, __shfl_xor(mx, 2, 64));
      mx = fmaxf(mx, __shfl_xor(mx, 4, 64));
      mx = fmaxf(mx, __shfl_xor(mx, 8, 64));
      float mnew = fmaxf(mrow[r], mx);
      float alpha = exp2f(mrow[r] - mnew);
      mrow[r] = mnew;
      lrow[r] *= alpha;
      oacc0[r] *= alpha;
      oacc1[r] *= alpha;
      float ps = 0.f;
#pragma unroll
      for (int t = 0; t < 4; ++t) {
        float p = exp2f(s[t][r] - mnew);
        ps += p;
        p_lds[wid][lg * 4 + r][t * 16 + lc] = f2bf(p);
      }
      lrow[r] += ps;
    }
#pragma unroll
    for (int mc = 0; mc < 2; ++mc) {
      ABF pa; pa.s = *(const s16x8*)(&p_lds[wid][lc][mc * 32 + lg * 8]);
      ABF vb0; vb0.s = *(const s16x8*)(vp + (size_t)(lc) * 1024 + kb + mc * 32 + lg * 8);
      ABF vb1; vb1.s = *(const s16x8*)(vp + (size_t)(16 + lc) * 1024 + kb + mc * 32 + lg * 8);
      oacc0 = __builtin_amdgcn_mfma_f32_16x16x32_bf16(pa.v, vb0.v, oacc0, 0, 0, 0);
      oacc1 = __builtin_amdgcn_mfma_f32_16x16x32_bf16(pa.v, vb1.v, oacc1, 0, 0, 0);
    }
  }
#pragma unroll
  for (int r = 0; r < 4; ++r) {
    float l = lrow[r];
    l += __shfl_xor(l, 1, 64);
    l += __shfl_xor(l, 2, 64);
    l += __shfl_xor(l, 4, 64);
    l += __shfl_xor(l, 8, 64);
    float inv = 1.0f / l;
    int q = qbase + lg * 4 + r;
    xat[(size_t)(b * 2048 + q) * 256 + h * 32 + lc] = f2bf(oacc0[r] * inv);
    xat[(size_t)(b * 2048 + q) * 256 + h * 32 + 16 + lc] = f2bf(oacc1[r] * inv);
  }
}

// final projection (16384x256, K=256) + bias -> f32 out
__global__ __launch_bounds__(256) void k_proj(const unsigned short* __restrict__ xat,
                                              const unsigned short* __restrict__ wb,
                                              const float* __restrict__ pb,
                                              float* __restrict__ out) {
  int tid = threadIdx.x;
  int wid = tid >> 6, lane = tid & 63, lg = lane >> 4, lc = lane & 15;
  int rowbase = blockIdx.x * 16;
  f32x4 acc[4] = {};
  const unsigned short* ap = xat + (size_t)(rowbase + lc) * 256 + lg * 8;
#pragma unroll
  for (int kc = 0; kc < 8; ++kc) {
    ABF a; a.s = *(const s16x8*)(ap + kc * 32);
#pragma unroll
    for (int t = 0; t < 4; ++t) {
      ABF bb; bb.s = *(const s16x8*)(wb + (size_t)(wid * 64 + t * 16 + lc) * 256 + kc * 32 + lg * 8);
      acc[t] = __builtin_amdgcn_mfma_f32_16x16x32_bf16(a.v, bb.v, acc[t], 0, 0, 0);
    }
  }
#pragma unroll
  for (int t = 0; t < 4; ++t) {
    int col = wid * 64 + t * 16 + lc;
    float bias = pb[col];
#pragma unroll
    for (int r = 0; r < 4; ++r) {
      int row = rowbase + lg * 4 + r;
      out[(size_t)row * 256 + col] = acc[t][r] + bias;
    }
  }
}

// ---------------- launch ----------------

extern "C" void kernel_launch(void* const* d_in, const int* in_sizes, int n_in,
                              void* d_out, int out_size, void* d_ws, size_t ws_size,
                              hipStream_t stream) {
  (void)in_sizes; (void)n_in; (void)out_size; (void)ws_size;
  const float* q_x         = (const float*)d_in[0];
  const float* kv_x        = (const float*)d_in[1];
  const float* token_score = (const float*)d_in[2];
  const int*   idx_token   = (const int*)d_in[3];
  const float* q_w         = (const float*)d_in[4];
  const float* kv_w        = (const float*)d_in[5];
  const float* proj_w      = (const float*)d_in[6];
  const float* proj_b      = (const float*)d_in[7];
  const float* sr_w        = (const float*)d_in[8];
  const float* sr_b        = (const float*)d_in[9];
  const float* ln_w        = (const float*)d_in[10];
  const float* ln_b        = (const float*)d_in[11];
  float* out = (float*)d_out;

  char* ws = (char*)d_ws;
  unsigned short* q_s   = (unsigned short*)(ws + 0);          // 64*2048*32  bf16 = 8 MB
  unsigned short* x4    = (unsigned short*)(ws + 8388608);    // 8192*1024   bf16 = 16 MB
  unsigned short* xat   = (unsigned short*)(ws + 8388608);    // aliases x4 (dead by attn time)
  unsigned short* w4t   = (unsigned short*)(ws + 25165824);   // 256*1024    bf16
  unsigned short* kv_ln = (unsigned short*)(ws + 25690112);   // 8192*256    bf16
  unsigned short* kmat  = (unsigned short*)(ws + 29884416);   // 64*1024*32  bf16
  unsigned short* vt    = (unsigned short*)(ws + 34078720);   // 64*32*1024  bf16
  float*          confp = (float*)(ws + 38273024);            // 8*1024      f32
  unsigned short* q_xb  = (unsigned short*)(ws + 38305792);   // 16384*256   bf16 = 8 MB
  unsigned short* q_wb  = (unsigned short*)(ws + 46694400);   // 256*256     bf16
  unsigned short* kv_wb = (unsigned short*)(ws + 46825472);   // 512*256     bf16
  unsigned short* p_wb  = (unsigned short*)(ws + 47087616);   // 256*256     bf16

  k_cvt_bf16<<<dim3(16384), dim3(256), 0, stream>>>(q_x, q_xb, 4194304);
  k_cvt_bf16<<<dim3(256), dim3(256), 0, stream>>>(q_w, q_wb, 65536);
  k_cvt_bf16<<<dim3(512), dim3(256), 0, stream>>>(kv_w, kv_wb, 131072);
  k_cvt_bf16<<<dim3(256), dim3(256), 0, stream>>>(proj_w, p_wb, 65536);
  k_repack_w4<<<dim3(1024), dim3(256), 0, stream>>>(sr_w, w4t);
  k_gather_x4<<<dim3(4096, 8), dim3(256), 0, stream>>>(kv_x, idx_token, x4);
  k_conf<<<dim3(32), dim3(256), 0, stream>>>(token_score, idx_token, confp);
  k_qproj<<<dim3(1024), dim3(256), 0, stream>>>(q_xb, q_wb, q_s);
  k_conv_ln<<<dim3(512), dim3(256), 0, stream>>>(x4, w4t, sr_b, ln_w, ln_b, kv_ln);
  k_kvproj<<<dim3(512), dim3(256), 0, stream>>>(kv_ln, kv_wb, kmat, vt);
  k_attn<<<dim3(32, 64), dim3(256), 0, stream>>>(q_s, kmat, vt, confp, xat);
  k_proj<<<dim3(1024), dim3(256), 0, stream>>>(xat, p_wb, proj_b, out);
}

// Round 2
// 195.717 us; speedup vs baseline: 1.2248x; 1.2248x over previous
//
#include <hip/hip_runtime.h>

#define LOG2E 1.4426950408889634f

typedef float f32x4 __attribute__((ext_vector_type(4)));
typedef short s16x8 __attribute__((ext_vector_type(8)));
typedef __bf16 bf16x8 __attribute__((ext_vector_type(8)));
typedef unsigned int u32x2 __attribute__((ext_vector_type(2)));

union ABF { s16x8 s; bf16x8 v; };
union PKU { unsigned int u[4]; s16x8 s; bf16x8 v; };

__device__ __forceinline__ unsigned short f2bf(float f) {
  unsigned int u = __builtin_bit_cast(unsigned int, f);
  u += 0x7fffu + ((u >> 16) & 1u);
  return (unsigned short)(u >> 16);
}

__device__ __forceinline__ unsigned int cvt_pk_bf16(float a, float b) {
  unsigned int r;
  asm("v_cvt_pk_bf16_f32 %0, %1, %2" : "=v"(r) : "v"(a), "v"(b));
  return r;  // low16 = bf16(a), high16 = bf16(b)
}

// ---------------- prep kernels ----------------

// merged f32->bf16 for the three plain weight matrices
__global__ __launch_bounds__(256) void k_cvt3(const float* __restrict__ a, unsigned short* __restrict__ da, int na,
                                              const float* __restrict__ b, unsigned short* __restrict__ db, int nb,
                                              const float* __restrict__ c, unsigned short* __restrict__ dc, int nc) {
  int i = blockIdx.x * 256 + threadIdx.x;
  if (i < na) { da[i] = f2bf(a[i]); return; }
  i -= na;
  if (i < nb) { db[i] = f2bf(b[i]); return; }
  i -= nb;
  if (i < nc) dc[i] = f2bf(c[i]);
}

// w4t[co][k], k = (dh*2+dw)*256 + ci ; from sr_w[co][ci][dh][dw]
__global__ __launch_bounds__(256) void k_repack_w4(const float* __restrict__ sr_w,
                                                   unsigned short* __restrict__ w4t) {
  int idx = blockIdx.x * 256 + threadIdx.x;  // 256*1024
  int co = idx >> 10, k = idx & 1023;
  int slot = k >> 8, ci = k & 255;
  int dh = slot >> 1, dw = slot & 1;
  w4t[idx] = f2bf(sr_w[((co * 256 + ci) * 2 + dh) * 2 + dw]);
}

// token2map gather, rearranged for conv-as-GEMM:
__global__ __launch_bounds__(256) void k_gather_x4(const float* __restrict__ kv_x,
                                                   const int* __restrict__ idx_token,
                                                   unsigned short* __restrict__ x4) {
  int b = blockIdx.y, i = blockIdx.x, c = threadIdx.x;
  int tok = idx_token[b * 4096 + i];
  int y = i >> 6, x = i & 63;
  int row = ((y >> 1) << 5) + (x >> 1);
  int slot = ((y & 1) << 1) + (x & 1);
  const float inv1 = 1.0f / 1.000001f;
  x4[(size_t)((b * 1024 + row) * 4 + slot) * 256 + c] =
      f2bf(kv_x[(size_t)(b * 2048 + tok) * 256 + c] * inv1);
}

// conf[b][m] = log2e * mean_{2x2}(token_score gathered) / 1.000001
__global__ __launch_bounds__(256) void k_conf(const float* __restrict__ token_score,
                                              const int* __restrict__ idx_token,
                                              float* __restrict__ conf) {
  int t = blockIdx.x * 256 + threadIdx.x;  // B*1024
  int b = t >> 10, m = t & 1023;
  int h = m >> 5, w = m & 31;
  float s = 0.f;
#pragma unroll
  for (int dh = 0; dh < 2; ++dh)
#pragma unroll
    for (int dw = 0; dw < 2; ++dw) {
      int i = (2 * h + dh) * 64 + (2 * w + dw);
      s += token_score[b * 2048 + idx_token[b * 4096 + i]];
    }
  conf[t] = s * 0.25f * (1.0f / 1.000001f) * LOG2E;
}

// ---------------- GEMM kernels (16 rows x block, 4 waves) ----------------

// q_s[(b*8+h)*2048 + n][d] = bf16( (q_x @ q_w^T) * SCALE * LOG2E ); reads f32 q_x directly
__global__ __launch_bounds__(256) void k_qproj(const float* __restrict__ xa,
                                               const unsigned short* __restrict__ wb,
                                               unsigned short* __restrict__ q_s) {
  int tid = threadIdx.x;
  int wid = tid >> 6, lane = tid & 63, lg = lane >> 4, lc = lane & 15;
  int rowbase = blockIdx.x * 16;
  f32x4 acc[4] = {};
  const float* ap = xa + (size_t)(rowbase + lc) * 256 + lg * 8;
#pragma unroll
  for (int kc = 0; kc < 8; ++kc) {
    f32x4 a0 = *(const f32x4*)(ap + kc * 32);
    f32x4 a1 = *(const f32x4*)(ap + kc * 32 + 4);
    PKU a;
    a.u[0] = cvt_pk_bf16(a0[0], a0[1]);
    a.u[1] = cvt_pk_bf16(a0[2], a0[3]);
    a.u[2] = cvt_pk_bf16(a1[0], a1[1]);
    a.u[3] = cvt_pk_bf16(a1[2], a1[3]);
#pragma unroll
    for (int t = 0; t < 4; ++t) {
      ABF bb; bb.s = *(const s16x8*)(wb + (size_t)(wid * 64 + t * 16 + lc) * 256 + kc * 32 + lg * 8);
      acc[t] = __builtin_amdgcn_mfma_f32_16x16x32_bf16(a.v, bb.v, acc[t], 0, 0, 0);
    }
  }
  const float qs = 0.17677669529663687f * LOG2E;
#pragma unroll
  for (int t = 0; t < 4; ++t) {
    int col = wid * 64 + t * 16 + lc;
    int h = col >> 5, d = col & 31;
#pragma unroll
    for (int r = 0; r < 4; ++r) {
      int row = rowbase + lg * 4 + r;
      int b = row >> 11, n = row & 2047;
      q_s[(size_t)((b * 8 + h) * 2048 + n) * 32 + d] = f2bf(acc[t][r] * qs);
    }
  }
}

// conv-as-GEMM (8192x256, K=1024) + bias + LayerNorm fused -> kv_ln bf16
__global__ __launch_bounds__(256) void k_conv_ln(const unsigned short* __restrict__ x4,
                                                 const unsigned short* __restrict__ w4t,
                                                 const float* __restrict__ sr_b,
                                                 const float* __restrict__ ln_w,
                                                 const float* __restrict__ ln_b,
                                                 unsigned short* __restrict__ kv_ln) {
  __shared__ float srow[16][260];
  int tid = threadIdx.x;
  int wid = tid >> 6, lane = tid & 63, lg = lane >> 4, lc = lane & 15;
  int rowbase = blockIdx.x * 16;
  f32x4 acc[4] = {};
  const unsigned short* ap = x4 + (size_t)(rowbase + lc) * 1024 + lg * 8;
  for (int kc = 0; kc < 32; ++kc) {
    ABF a; a.s = *(const s16x8*)(ap + kc * 32);
#pragma unroll
    for (int t = 0; t < 4; ++t) {
      ABF bb; bb.s = *(const s16x8*)(w4t + (size_t)(wid * 64 + t * 16 + lc) * 1024 + kc * 32 + lg * 8);
      acc[t] = __builtin_amdgcn_mfma_f32_16x16x32_bf16(a.v, bb.v, acc[t], 0, 0, 0);
    }
  }
#pragma unroll
  for (int t = 0; t < 4; ++t) {
    int col = wid * 64 + t * 16 + lc;
    float bias = sr_b[col];
#pragma unroll
    for (int r = 0; r < 4; ++r) srow[lg * 4 + r][col] = acc[t][r] + bias;
  }
  __syncthreads();
  int r = tid >> 4, c16 = tid & 15;
  float vals[16];
  float s = 0.f, ss = 0.f;
#pragma unroll
  for (int i = 0; i < 16; ++i) {
    float v = srow[r][c16 * 16 + i];
    vals[i] = v; s += v; ss += v * v;
  }
#pragma unroll
  for (int m = 1; m < 16; m <<= 1) {
    s += __shfl_xor(s, m, 64);
    ss += __shfl_xor(ss, m, 64);
  }
  float mu = s * (1.0f / 256.0f);
  float var = ss * (1.0f / 256.0f) - mu * mu;
  float rstd = rsqrtf(var + 1e-5f);
  s16x8 o0, o1;
#pragma unroll
  for (int i = 0; i < 8; ++i) {
    int c = c16 * 16 + i;
    o0[i] = (short)f2bf((vals[i] - mu) * rstd * ln_w[c] + ln_b[c]);
  }
#pragma unroll
  for (int i = 0; i < 8; ++i) {
    int c = c16 * 16 + 8 + i;
    o1[i] = (short)f2bf((vals[8 + i] - mu) * rstd * ln_w[c] + ln_b[c]);
  }
  *(s16x8*)(kv_ln + (size_t)(rowbase + r) * 256 + c16 * 16) = o0;
  *(s16x8*)(kv_ln + (size_t)(rowbase + r) * 256 + c16 * 16 + 8) = o1;
}

// kv projection (8192x512, K=256)
__global__ __launch_bounds__(256) void k_kvproj(const unsigned short* __restrict__ kv_ln,
                                                const unsigned short* __restrict__ wb,
                                                unsigned short* __restrict__ kmat,
                                                unsigned short* __restrict__ vt) {
  int tid = threadIdx.x;
  int wid = tid >> 6, lane = tid & 63, lg = lane >> 4, lc = lane & 15;
  int rowbase = blockIdx.x * 16;
  f32x4 acc[8] = {};
  const unsigned short* ap = kv_ln + (size_t)(rowbase + lc) * 256 + lg * 8;
#pragma unroll
  for (int kc = 0; kc < 8; ++kc) {
    ABF a; a.s = *(const s16x8*)(ap + kc * 32);
#pragma unroll
    for (int t = 0; t < 8; ++t) {
      ABF bb; bb.s = *(const s16x8*)(wb + (size_t)(wid * 128 + t * 16 + lc) * 256 + kc * 32 + lg * 8);
      acc[t] = __builtin_amdgcn_mfma_f32_16x16x32_bf16(a.v, bb.v, acc[t], 0, 0, 0);
    }
  }
#pragma unroll
  for (int t = 0; t < 8; ++t) {
    int j = wid * 128 + t * 16 + lc;
    int sflag = j >> 8, h = (j >> 5) & 7, d = j & 31;
#pragma unroll
    for (int r = 0; r < 4; ++r) {
      int row = rowbase + lg * 4 + r;
      int b = row >> 10, m = row & 1023;
      unsigned short v = f2bf(acc[t][r]);
      if (sflag == 0) kmat[(size_t)((b * 8 + h) * 1024 + m) * 32 + d] = v;
      else            vt[(size_t)((b * 8 + h) * 32 + d) * 1024 + m] = v;
    }
  }
}

// ---------------- flash attention (swapped QK^T, max-free log2 softmax) ----------------
// grid (16 qtiles, 64 bh), 4 waves x 32 q-rows each (2 q-frags share K/V frags).
__global__ __launch_bounds__(256) void k_attn(const unsigned short* __restrict__ q_s,
                                              const unsigned short* __restrict__ kmat,
                                              const unsigned short* __restrict__ vt,
                                              const float* __restrict__ conf,
                                              unsigned short* __restrict__ xat) {
  __shared__ __align__(16) unsigned short p_lds[4][2][16][72];
  int tid = threadIdx.x;
  int wid = tid >> 6, lane = tid & 63, lg = lane >> 4, lc = lane & 15;
  int bh = blockIdx.y, b = bh >> 3, h = bh & 7;
  int qbase = blockIdx.x * 128 + wid * 32;

  ABF qf[2];
  qf[0].s = *(const s16x8*)(q_s + (size_t)(bh * 2048 + qbase + lc) * 32 + lg * 8);
  qf[1].s = *(const s16x8*)(q_s + (size_t)(bh * 2048 + qbase + 16 + lc) * 32 + lg * 8);
  f32x4 oacc[2][2] = {};
  float lsum[2] = {0.f, 0.f};
  const float* cfp = conf + b * 1024;
  const unsigned short* kp = kmat + (size_t)bh * 1024 * 32;
  const unsigned short* vp = vt + (size_t)bh * 32 * 1024;

  for (int kb = 0; kb < 1024; kb += 64) {
    ABF kf[4]; f32x4 c4[4];
#pragma unroll
    for (int t = 0; t < 4; ++t) {
      kf[t].s = *(const s16x8*)(kp + (size_t)(kb + t * 16 + lc) * 32 + lg * 8);
      c4[t] = *(const f32x4*)(cfp + kb + t * 16 + lg * 4);
    }
    ABF vb[2][2];
#pragma unroll
    for (int c = 0; c < 2; ++c)
#pragma unroll
      for (int dh = 0; dh < 2; ++dh)
        vb[c][dh].s = *(const s16x8*)(vp + (size_t)(dh * 16 + lc) * 1024 + kb + c * 32 + lg * 8);

    // swapped QK^T: S^T[k][q]; lane holds q=lc, k = kb + t*16 + lg*4 + r
#pragma unroll
    for (int g = 0; g < 2; ++g) {
#pragma unroll
      for (int t = 0; t < 4; ++t) {
        f32x4 st = __builtin_amdgcn_mfma_f32_16x16x32_bf16(kf[t].v, qf[g].v, c4[t], 0, 0, 0);
        f32x4 pt;
        pt[0] = exp2f(st[0]); pt[1] = exp2f(st[1]);
        pt[2] = exp2f(st[2]); pt[3] = exp2f(st[3]);
        lsum[g] += (pt[0] + pt[1]) + (pt[2] + pt[3]);
        u32x2 w;
        w.x = cvt_pk_bf16(pt[0], pt[1]);
        w.y = cvt_pk_bf16(pt[2], pt[3]);
        *(u32x2*)(&p_lds[wid][g][lc][t * 16 + lg * 4]) = w;
      }
    }
    // PV: A = P[q=lc][k chunks], B = V^T rows
#pragma unroll
    for (int g = 0; g < 2; ++g) {
      ABF pa0, pa1;
      pa0.s = *(const s16x8*)(&p_lds[wid][g][lc][lg * 8]);
      pa1.s = *(const s16x8*)(&p_lds[wid][g][lc][32 + lg * 8]);
      oacc[g][0] = __builtin_amdgcn_mfma_f32_16x16x32_bf16(pa0.v, vb[0][0].v, oacc[g][0], 0, 0, 0);
      oacc[g][1] = __builtin_amdgcn_mfma_f32_16x16x32_bf16(pa0.v, vb[0][1].v, oacc[g][1], 0, 0, 0);
      oacc[g][0] = __builtin_amdgcn_mfma_f32_16x16x32_bf16(pa1.v, vb[1][0].v, oacc[g][0], 0, 0, 0);
      oacc[g][1] = __builtin_amdgcn_mfma_f32_16x16x32_bf16(pa1.v, vb[1][1].v, oacc[g][1], 0, 0, 0);
    }
  }

#pragma unroll
  for (int g = 0; g < 2; ++g) {
    float l = lsum[g];
    l += __shfl_xor(l, 16, 64);
    l += __shfl_xor(l, 32, 64);
    float inv = 1.0f / l;
#pragma unroll
    for (int r = 0; r < 4; ++r) {
      float invr = __shfl(inv, lg * 4 + r, 64);
      int q = qbase + g * 16 + lg * 4 + r;
      xat[(size_t)(b * 2048 + q) * 256 + h * 32 + lc] = f2bf(oacc[g][0][r] * invr);
      xat[(size_t)(b * 2048 + q) * 256 + h * 32 + 16 + lc] = f2bf(oacc[g][1][r] * invr);
    }
  }
}

// final projection (16384x256, K=256) + bias -> f32 out
__global__ __launch_bounds__(256) void k_proj(const unsigned short* __restrict__ xat,
                                              const unsigned short* __restrict__ wb,
                                              const float* __restrict__ pb,
                                              float* __restrict__ out) {
  int tid = threadIdx.x;
  int wid = tid >> 6, lane = tid & 63, lg = lane >> 4, lc = lane & 15;
  int rowbase = blockIdx.x * 16;
  f32x4 acc[4] = {};
  const unsigned short* ap = xat + (size_t)(rowbase + lc) * 256 + lg * 8;
#pragma unroll
  for (int kc = 0; kc < 8; ++kc) {
    ABF a; a.s = *(const s16x8*)(ap + kc * 32);
#pragma unroll
    for (int t = 0; t < 4; ++t) {
      ABF bb; bb.s = *(const s16x8*)(wb + (size_t)(wid * 64 + t * 16 + lc) * 256 + kc * 32 + lg * 8);
      acc[t] = __builtin_amdgcn_mfma_f32_16x16x32_bf16(a.v, bb.v, acc[t], 0, 0, 0);
    }
  }
#pragma unroll
  for (int t = 0; t < 4; ++t) {
    int col = wid * 64 + t * 16 + lc;
    float bias = pb[col];
#pragma unroll
    for (int r = 0; r < 4; ++r) {
      int row = rowbase + lg * 4 + r;
      out[(size_t)row * 256 + col] = acc[t][r] + bias;
    }
  }
}

// ---------------- launch ----------------

extern "C" void kernel_launch(void* const* d_in, const int* in_sizes, int n_in,
                              void* d_out, int out_size, void* d_ws, size_t ws_size,
                              hipStream_t stream) {
  (void)in_sizes; (void)n_in; (void)out_size; (void)ws_size;
  const float* q_x         = (const float*)d_in[0];
  const float* kv_x        = (const float*)d_in[1];
  const float* token_score = (const float*)d_in[2];
  const int*   idx_token   = (const int*)d_in[3];
  const float* q_w         = (const float*)d_in[4];
  const float* kv_w        = (const float*)d_in[5];
  const float* proj_w      = (const float*)d_in[6];
  const float* proj_b      = (const float*)d_in[7];
  const float* sr_w        = (const float*)d_in[8];
  const float* sr_b        = (const float*)d_in[9];
  const float* ln_w        = (const float*)d_in[10];
  const float* ln_b        = (const float*)d_in[11];
  float* out = (float*)d_out;

  char* ws = (char*)d_ws;
  unsigned short* q_s   = (unsigned short*)(ws + 0);          // 64*2048*32  bf16 = 8 MB
  unsigned short* x4    = (unsigned short*)(ws + 8388608);    // 8192*1024   bf16 = 16 MB
  unsigned short* xat   = (unsigned short*)(ws + 8388608);    // aliases x4 (dead by attn time)
  unsigned short* w4t   = (unsigned short*)(ws + 25165824);   // 256*1024    bf16
  unsigned short* kv_ln = (unsigned short*)(ws + 25690112);   // 8192*256    bf16
  unsigned short* kmat  = (unsigned short*)(ws + 29884416);   // 64*1024*32  bf16
  unsigned short* vt    = (unsigned short*)(ws + 34078720);   // 64*32*1024  bf16
  float*          confp = (float*)(ws + 38273024);            // 8*1024      f32
  unsigned short* q_wb  = (unsigned short*)(ws + 46694400);   // 256*256     bf16
  unsigned short* kv_wb = (unsigned short*)(ws + 46825472);   // 512*256     bf16
  unsigned short* p_wb  = (unsigned short*)(ws + 47087616);   // 256*256     bf16

  k_cvt3<<<dim3(1024), dim3(256), 0, stream>>>(q_w, q_wb, 65536,
                                               kv_w, kv_wb, 131072,
                                               proj_w, p_wb, 65536);
  k_repack_w4<<<dim3(1024), dim3(256), 0, stream>>>(sr_w, w4t);
  k_gather_x4<<<dim3(4096, 8), dim3(256), 0, stream>>>(kv_x, idx_token, x4);
  k_conf<<<dim3(32), dim3(256), 0, stream>>>(token_score, idx_token, confp);
  k_qproj<<<dim3(1024), dim3(256), 0, stream>>>(q_x, q_wb, q_s);
  k_conv_ln<<<dim3(512), dim3(256), 0, stream>>>(x4, w4t, sr_b, ln_w, ln_b, kv_ln);
  k_kvproj<<<dim3(512), dim3(256), 0, stream>>>(kv_ln, kv_wb, kmat, vt);
  k_attn<<<dim3(16, 64), dim3(256), 0, stream>>>(q_s, kmat, vt, confp, xat);
  k_proj<<<dim3(1024), dim3(256), 0, stream>>>(xat, p_wb, proj_b, out);
}

// Round 3
// 181.669 us; speedup vs baseline: 1.3195x; 1.0773x over previous
//
#include <hip/hip_runtime.h>

#define LOG2E 1.4426950408889634f

typedef float f32x4 __attribute__((ext_vector_type(4)));
typedef short s16x8 __attribute__((ext_vector_type(8)));
typedef __bf16 bf16x8 __attribute__((ext_vector_type(8)));
typedef unsigned int u32x2 __attribute__((ext_vector_type(2)));

union ABF { s16x8 s; bf16x8 v; };
union PKU { unsigned int u[4]; s16x8 s; bf16x8 v; };

__device__ __forceinline__ unsigned short f2bf(float f) {
  unsigned int u = __builtin_bit_cast(unsigned int, f);
  u += 0x7fffu + ((u >> 16) & 1u);
  return (unsigned short)(u >> 16);
}

__device__ __forceinline__ unsigned int cvt_pk_bf16(float a, float b) {
  unsigned int r;
  asm("v_cvt_pk_bf16_f32 %0, %1, %2" : "=v"(r) : "v"(a), "v"(b));
  return r;  // low16 = bf16(a), high16 = bf16(b)
}

// ---------------- fused prep: weight converts + conv-weight repack + conf ----------------

__global__ __launch_bounds__(256) void k_prep(const float* __restrict__ q_w,
                                              const float* __restrict__ kv_w,
                                              const float* __restrict__ proj_w,
                                              const float* __restrict__ sr_w,
                                              const float* __restrict__ token_score,
                                              const int* __restrict__ idx_token,
                                              unsigned short* __restrict__ q_wb,
                                              unsigned short* __restrict__ kv_wb,
                                              unsigned short* __restrict__ p_wb,
                                              unsigned short* __restrict__ w4t,
                                              float* __restrict__ conf) {
  int bid = blockIdx.x, t = threadIdx.x;
  if (bid < 256) { int i = bid * 256 + t; q_wb[i] = f2bf(q_w[i]); return; }
  if (bid < 768) { int i = (bid - 256) * 256 + t; kv_wb[i] = f2bf(kv_w[i]); return; }
  if (bid < 1024) { int i = (bid - 768) * 256 + t; p_wb[i] = f2bf(proj_w[i]); return; }
  if (bid < 2048) {
    // w4t[co][k], k = (dh*2+dw)*256 + ci ; from sr_w[co][ci][dh][dw]
    int idx = (bid - 1024) * 256 + t;
    int co = idx >> 10, k = idx & 1023;
    int slot = k >> 8, ci = k & 255;
    int dh = slot >> 1, dw = slot & 1;
    w4t[idx] = f2bf(sr_w[((co * 256 + ci) * 2 + dh) * 2 + dw]);
    return;
  }
  // conf[b][m] = log2e * mean_{2x2}(token_score gathered) / 1.000001
  int i = (bid - 2048) * 256 + t;  // B*1024 = 8192
  int b = i >> 10, m = i & 1023;
  int h = m >> 5, w = m & 31;
  float s = 0.f;
#pragma unroll
  for (int dh = 0; dh < 2; ++dh)
#pragma unroll
    for (int dw = 0; dw < 2; ++dw) {
      int j = (2 * h + dh) * 64 + (2 * w + dw);
      s += token_score[b * 2048 + idx_token[b * 4096 + j]];
    }
  conf[i] = s * 0.25f * (1.0f / 1.000001f) * LOG2E;
}

// token2map gather, rearranged for conv-as-GEMM; 4 rows/block, f32x4 vectorized
__global__ __launch_bounds__(256) void k_gather_x4(const float* __restrict__ kv_x,
                                                   const int* __restrict__ idx_token,
                                                   unsigned short* __restrict__ x4) {
  int gi = blockIdx.x * 4 + (threadIdx.x >> 6);  // 0..32767
  int c4i = threadIdx.x & 63;
  int b = gi >> 12, i = gi & 4095;
  int tok = idx_token[gi];
  int y = i >> 6, x = i & 63;
  int row = ((y >> 1) << 5) + (x >> 1);
  int slot = ((y & 1) << 1) + (x & 1);
  const float inv1 = 1.0f / 1.000001f;
  f32x4 v = *(const f32x4*)(kv_x + (size_t)(b * 2048 + tok) * 256 + c4i * 4);
  u32x2 w;
  w.x = cvt_pk_bf16(v[0] * inv1, v[1] * inv1);
  w.y = cvt_pk_bf16(v[2] * inv1, v[3] * inv1);
  *(u32x2*)(x4 + (size_t)((b * 1024 + row) * 4 + slot) * 256 + c4i * 4) = w;
}

// ---------------- GEMM kernels (16 rows x block, 4 waves) ----------------

// q_s[(b*8+h)*2048 + n][d] = bf16( (q_x @ q_w^T) * SCALE * LOG2E ); reads f32 q_x directly
__global__ __launch_bounds__(256) void k_qproj(const float* __restrict__ xa,
                                               const unsigned short* __restrict__ wb,
                                               unsigned short* __restrict__ q_s) {
  int tid = threadIdx.x;
  int wid = tid >> 6, lane = tid & 63, lg = lane >> 4, lc = lane & 15;
  int rowbase = blockIdx.x * 16;
  f32x4 acc[4] = {};
  const float* ap = xa + (size_t)(rowbase + lc) * 256 + lg * 8;
#pragma unroll
  for (int kc = 0; kc < 8; ++kc) {
    f32x4 a0 = *(const f32x4*)(ap + kc * 32);
    f32x4 a1 = *(const f32x4*)(ap + kc * 32 + 4);
    PKU a;
    a.u[0] = cvt_pk_bf16(a0[0], a0[1]);
    a.u[1] = cvt_pk_bf16(a0[2], a0[3]);
    a.u[2] = cvt_pk_bf16(a1[0], a1[1]);
    a.u[3] = cvt_pk_bf16(a1[2], a1[3]);
#pragma unroll
    for (int t = 0; t < 4; ++t) {
      ABF bb; bb.s = *(const s16x8*)(wb + (size_t)(wid * 64 + t * 16 + lc) * 256 + kc * 32 + lg * 8);
      acc[t] = __builtin_amdgcn_mfma_f32_16x16x32_bf16(a.v, bb.v, acc[t], 0, 0, 0);
    }
  }
  const float qs = 0.17677669529663687f * LOG2E;
#pragma unroll
  for (int t = 0; t < 4; ++t) {
    int col = wid * 64 + t * 16 + lc;
    int h = col >> 5, d = col & 31;
#pragma unroll
    for (int r = 0; r < 4; ++r) {
      int row = rowbase + lg * 4 + r;
      int b = row >> 11, n = row & 2047;
      q_s[(size_t)((b * 8 + h) * 2048 + n) * 32 + d] = f2bf(acc[t][r] * qs);
    }
  }
}

// conv-as-GEMM (8192x256, K=1024) + bias + LayerNorm fused -> kv_ln bf16
__global__ __launch_bounds__(256) void k_conv_ln(const unsigned short* __restrict__ x4,
                                                 const unsigned short* __restrict__ w4t,
                                                 const float* __restrict__ sr_b,
                                                 const float* __restrict__ ln_w,
                                                 const float* __restrict__ ln_b,
                                                 unsigned short* __restrict__ kv_ln) {
  __shared__ float srow[16][260];
  int tid = threadIdx.x;
  int wid = tid >> 6, lane = tid & 63, lg = lane >> 4, lc = lane & 15;
  int rowbase = blockIdx.x * 16;
  f32x4 acc[4] = {};
  const unsigned short* ap = x4 + (size_t)(rowbase + lc) * 1024 + lg * 8;
  for (int kc = 0; kc < 32; ++kc) {
    ABF a; a.s = *(const s16x8*)(ap + kc * 32);
#pragma unroll
    for (int t = 0; t < 4; ++t) {
      ABF bb; bb.s = *(const s16x8*)(w4t + (size_t)(wid * 64 + t * 16 + lc) * 1024 + kc * 32 + lg * 8);
      acc[t] = __builtin_amdgcn_mfma_f32_16x16x32_bf16(a.v, bb.v, acc[t], 0, 0, 0);
    }
  }
#pragma unroll
  for (int t = 0; t < 4; ++t) {
    int col = wid * 64 + t * 16 + lc;
    float bias = sr_b[col];
#pragma unroll
    for (int r = 0; r < 4; ++r) srow[lg * 4 + r][col] = acc[t][r] + bias;
  }
  __syncthreads();
  int r = tid >> 4, c16 = tid & 15;
  float vals[16];
  float s = 0.f, ss = 0.f;
#pragma unroll
  for (int i = 0; i < 16; ++i) {
    float v = srow[r][c16 * 16 + i];
    vals[i] = v; s += v; ss += v * v;
  }
#pragma unroll
  for (int m = 1; m < 16; m <<= 1) {
    s += __shfl_xor(s, m, 64);
    ss += __shfl_xor(ss, m, 64);
  }
  float mu = s * (1.0f / 256.0f);
  float var = ss * (1.0f / 256.0f) - mu * mu;
  float rstd = rsqrtf(var + 1e-5f);
  s16x8 o0, o1;
#pragma unroll
  for (int i = 0; i < 8; ++i) {
    int c = c16 * 16 + i;
    o0[i] = (short)f2bf((vals[i] - mu) * rstd * ln_w[c] + ln_b[c]);
  }
#pragma unroll
  for (int i = 0; i < 8; ++i) {
    int c = c16 * 16 + 8 + i;
    o1[i] = (short)f2bf((vals[8 + i] - mu) * rstd * ln_w[c] + ln_b[c]);
  }
  *(s16x8*)(kv_ln + (size_t)(rowbase + r) * 256 + c16 * 16) = o0;
  *(s16x8*)(kv_ln + (size_t)(rowbase + r) * 256 + c16 * 16 + 8) = o1;
}

// kv projection (8192x512, K=256)
__global__ __launch_bounds__(256) void k_kvproj(const unsigned short* __restrict__ kv_ln,
                                                const unsigned short* __restrict__ wb,
                                                unsigned short* __restrict__ kmat,
                                                unsigned short* __restrict__ vt) {
  int tid = threadIdx.x;
  int wid = tid >> 6, lane = tid & 63, lg = lane >> 4, lc = lane & 15;
  int rowbase = blockIdx.x * 16;
  f32x4 acc[8] = {};
  const unsigned short* ap = kv_ln + (size_t)(rowbase + lc) * 256 + lg * 8;
#pragma unroll
  for (int kc = 0; kc < 8; ++kc) {
    ABF a; a.s = *(const s16x8*)(ap + kc * 32);
#pragma unroll
    for (int t = 0; t < 8; ++t) {
      ABF bb; bb.s = *(const s16x8*)(wb + (size_t)(wid * 128 + t * 16 + lc) * 256 + kc * 32 + lg * 8);
      acc[t] = __builtin_amdgcn_mfma_f32_16x16x32_bf16(a.v, bb.v, acc[t], 0, 0, 0);
    }
  }
#pragma unroll
  for (int t = 0; t < 8; ++t) {
    int j = wid * 128 + t * 16 + lc;
    int sflag = j >> 8, h = (j >> 5) & 7, d = j & 31;
#pragma unroll
    for (int r = 0; r < 4; ++r) {
      int row = rowbase + lg * 4 + r;
      int b = row >> 10, m = row & 1023;
      unsigned short v = f2bf(acc[t][r]);
      if (sflag == 0) kmat[(size_t)((b * 8 + h) * 1024 + m) * 32 + d] = v;
      else            vt[(size_t)((b * 8 + h) * 32 + d) * 1024 + m] = v;
    }
  }
}

// ---------------- flash attention (swapped QK^T, max-free log2 softmax) ----------------
// grid 1024 blocks (XCD-swizzled), 4 waves x 32 q-rows each.
__global__ __launch_bounds__(256, 4) void k_attn(const unsigned short* __restrict__ q_s,
                                                 const unsigned short* __restrict__ kmat,
                                                 const unsigned short* __restrict__ vt,
                                                 const float* __restrict__ conf,
                                                 unsigned short* __restrict__ xat) {
  __shared__ __align__(16) unsigned short p_lds[4 * 2 * 16 * 64];
  int tid = threadIdx.x;
  int wid = tid >> 6, lane = tid & 63, lg = lane >> 4, lc = lane & 15;
  // XCD swizzle: 8 heads per XCD, all 16 q-tiles of a head on the same XCD
  int bid = blockIdx.x;
  int xcd = bid & 7, slot = bid >> 3;
  int bh = xcd * 8 + (slot >> 4);
  int qt = slot & 15;
  int b = bh >> 3, h = bh & 7;
  int qbase = qt * 128 + wid * 32;

  ABF qf[2];
  qf[0].s = *(const s16x8*)(q_s + (size_t)(bh * 2048 + qbase + lc) * 32 + lg * 8);
  qf[1].s = *(const s16x8*)(q_s + (size_t)(bh * 2048 + qbase + 16 + lc) * 32 + lg * 8);

  ABF ones;
#pragma unroll
  for (int i = 0; i < 8; ++i) ones.s[i] = (short)0x3F80;  // bf16 1.0

  f32x4 oacc[2][2] = {};
  f32x4 lacc[2] = {};

  // strength-reduced per-lane pointers
  const unsigned short* kpl = kmat + (size_t)bh * 32768 + (size_t)lc * 32 + lg * 8;
  const float* cfl = conf + b * 1024 + lg * 4;
  const unsigned short* vpl0 = vt + (size_t)bh * 32768 + (size_t)lc * 1024 + lg * 8;
  const unsigned short* vpl1 = vpl0 + 16 * 1024;

  // swizzled LDS offsets (shorts). row = lc (128 B), slot' = slot ^ (lc&7)
  unsigned short* ldsrow = p_lds + (size_t)(wid * 2 * 16 + lc) * 64;
  int sw = lc & 7;
  int w_off[4], r_off[2];
#pragma unroll
  for (int t = 0; t < 4; ++t)
    w_off[t] = (((2 * t + (lg >> 1)) ^ sw) << 3) + ((lg & 1) << 2);
#pragma unroll
  for (int p = 0; p < 2; ++p)
    r_off[p] = ((p * 4 + lg) ^ sw) << 3;

#pragma unroll
  for (int kb = 0; kb < 1024; kb += 64) {
    ABF kf[4]; f32x4 c4[4];
#pragma unroll
    for (int t = 0; t < 4; ++t) {
      kf[t].s = *(const s16x8*)(kpl + kb * 32 + t * 512);
      c4[t] = *(const f32x4*)(cfl + kb + t * 16);
    }
    ABF vb[2][2];
#pragma unroll
    for (int c = 0; c < 2; ++c) {
      vb[c][0].s = *(const s16x8*)(vpl0 + kb + c * 32);
      vb[c][1].s = *(const s16x8*)(vpl1 + kb + c * 32);
    }
    // swapped QK^T: lane holds q=lc, k rows
#pragma unroll
    for (int g = 0; g < 2; ++g) {
      unsigned short* lrow = ldsrow + g * 1024;
#pragma unroll
      for (int t = 0; t < 4; ++t) {
        f32x4 st = __builtin_amdgcn_mfma_f32_16x16x32_bf16(kf[t].v, qf[g].v, c4[t], 0, 0, 0);
        f32x4 pt;
        pt[0] = __builtin_amdgcn_exp2f(st[0]);
        pt[1] = __builtin_amdgcn_exp2f(st[1]);
        pt[2] = __builtin_amdgcn_exp2f(st[2]);
        pt[3] = __builtin_amdgcn_exp2f(st[3]);
        u32x2 w;
        w.x = cvt_pk_bf16(pt[0], pt[1]);
        w.y = cvt_pk_bf16(pt[2], pt[3]);
        *(u32x2*)(lrow + w_off[t]) = w;
      }
    }
    // PV + row-sum via ones-MFMA
#pragma unroll
    for (int g = 0; g < 2; ++g) {
      unsigned short* lrow = ldsrow + g * 1024;
      ABF pa0, pa1;
      pa0.s = *(const s16x8*)(lrow + r_off[0]);
      pa1.s = *(const s16x8*)(lrow + r_off[1]);
      oacc[g][0] = __builtin_amdgcn_mfma_f32_16x16x32_bf16(pa0.v, vb[0][0].v, oacc[g][0], 0, 0, 0);
      oacc[g][1] = __builtin_amdgcn_mfma_f32_16x16x32_bf16(pa0.v, vb[0][1].v, oacc[g][1], 0, 0, 0);
      lacc[g]    = __builtin_amdgcn_mfma_f32_16x16x32_bf16(pa0.v, ones.v,     lacc[g],    0, 0, 0);
      oacc[g][0] = __builtin_amdgcn_mfma_f32_16x16x32_bf16(pa1.v, vb[1][0].v, oacc[g][0], 0, 0, 0);
      oacc[g][1] = __builtin_amdgcn_mfma_f32_16x16x32_bf16(pa1.v, vb[1][1].v, oacc[g][1], 0, 0, 0);
      lacc[g]    = __builtin_amdgcn_mfma_f32_16x16x32_bf16(pa1.v, ones.v,     lacc[g],    0, 0, 0);
    }
  }

#pragma unroll
  for (int g = 0; g < 2; ++g) {
#pragma unroll
    for (int r = 0; r < 4; ++r) {
      float inv = 1.0f / lacc[g][r];
      int q = qbase + g * 16 + lg * 4 + r;
      xat[(size_t)(b * 2048 + q) * 256 + h * 32 + lc] = f2bf(oacc[g][0][r] * inv);
      xat[(size_t)(b * 2048 + q) * 256 + h * 32 + 16 + lc] = f2bf(oacc[g][1][r] * inv);
    }
  }
}

// final projection (16384x256, K=256) + bias -> f32 out
__global__ __launch_bounds__(256) void k_proj(const unsigned short* __restrict__ xat,
                                              const unsigned short* __restrict__ wb,
                                              const float* __restrict__ pb,
                                              float* __restrict__ out) {
  int tid = threadIdx.x;
  int wid = tid >> 6, lane = tid & 63, lg = lane >> 4, lc = lane & 15;
  int rowbase = blockIdx.x * 16;
  f32x4 acc[4] = {};
  const unsigned short* ap = xat + (size_t)(rowbase + lc) * 256 + lg * 8;
#pragma unroll
  for (int kc = 0; kc < 8; ++kc) {
    ABF a; a.s = *(const s16x8*)(ap + kc * 32);
#pragma unroll
    for (int t = 0; t < 4; ++t) {
      ABF bb; bb.s = *(const s16x8*)(wb + (size_t)(wid * 64 + t * 16 + lc) * 256 + kc * 32 + lg * 8);
      acc[t] = __builtin_amdgcn_mfma_f32_16x16x32_bf16(a.v, bb.v, acc[t], 0, 0, 0);
    }
  }
#pragma unroll
  for (int t = 0; t < 4; ++t) {
    int col = wid * 64 + t * 16 + lc;
    float bias = pb[col];
#pragma unroll
    for (int r = 0; r < 4; ++r) {
      int row = rowbase + lg * 4 + r;
      out[(size_t)row * 256 + col] = acc[t][r] + bias;
    }
  }
}

// ---------------- launch ----------------

extern "C" void kernel_launch(void* const* d_in, const int* in_sizes, int n_in,
                              void* d_out, int out_size, void* d_ws, size_t ws_size,
                              hipStream_t stream) {
  (void)in_sizes; (void)n_in; (void)out_size; (void)ws_size;
  const float* q_x         = (const float*)d_in[0];
  const float* kv_x        = (const float*)d_in[1];
  const float* token_score = (const float*)d_in[2];
  const int*   idx_token   = (const int*)d_in[3];
  const float* q_w         = (const float*)d_in[4];
  const float* kv_w        = (const float*)d_in[5];
  const float* proj_w      = (const float*)d_in[6];
  const float* proj_b      = (const float*)d_in[7];
  const float* sr_w        = (const float*)d_in[8];
  const float* sr_b        = (const float*)d_in[9];
  const float* ln_w        = (const float*)d_in[10];
  const float* ln_b        = (const float*)d_in[11];
  float* out = (float*)d_out;

  char* ws = (char*)d_ws;
  unsigned short* q_s   = (unsigned short*)(ws + 0);          // 64*2048*32  bf16 = 8 MB
  unsigned short* x4    = (unsigned short*)(ws + 8388608);    // 8192*1024   bf16 = 16 MB
  unsigned short* xat   = (unsigned short*)(ws + 8388608);    // aliases x4 (dead by attn time)
  unsigned short* w4t   = (unsigned short*)(ws + 25165824);   // 256*1024    bf16
  unsigned short* kv_ln = (unsigned short*)(ws + 25690112);   // 8192*256    bf16
  unsigned short* kmat  = (unsigned short*)(ws + 29884416);   // 64*1024*32  bf16
  unsigned short* vt    = (unsigned short*)(ws + 34078720);   // 64*32*1024  bf16
  float*          confp = (float*)(ws + 38273024);            // 8*1024      f32
  unsigned short* q_wb  = (unsigned short*)(ws + 46694400);   // 256*256     bf16
  unsigned short* kv_wb = (unsigned short*)(ws + 46825472);   // 512*256     bf16
  unsigned short* p_wb  = (unsigned short*)(ws + 47087616);   // 256*256     bf16

  k_prep<<<dim3(2080), dim3(256), 0, stream>>>(q_w, kv_w, proj_w, sr_w, token_score, idx_token,
                                               q_wb, kv_wb, p_wb, w4t, confp);
  k_gather_x4<<<dim3(8192), dim3(256), 0, stream>>>(kv_x, idx_token, x4);
  k_qproj<<<dim3(1024), dim3(256), 0, stream>>>(q_x, q_wb, q_s);
  k_conv_ln<<<dim3(512), dim3(256), 0, stream>>>(x4, w4t, sr_b, ln_w, ln_b, kv_ln);
  k_kvproj<<<dim3(512), dim3(256), 0, stream>>>(kv_ln, kv_wb, kmat, vt);
  k_attn<<<dim3(1024), dim3(256), 0, stream>>>(q_s, kmat, vt, confp, xat);
  k_proj<<<dim3(1024), dim3(256), 0, stream>>>(xat, p_wb, proj_b, out);
}

// Round 4
// 119.159 us; speedup vs baseline: 2.0116x; 1.5246x over previous
//
#include <hip/hip_runtime.h>

#define LOG2E 1.4426950408889634f

typedef float f32x4 __attribute__((ext_vector_type(4)));
typedef short s16x8 __attribute__((ext_vector_type(8)));
typedef __bf16 bf16x8 __attribute__((ext_vector_type(8)));
typedef unsigned int u32x2 __attribute__((ext_vector_type(2)));

union ABF { s16x8 s; bf16x8 v; };
union PKU { unsigned int u[4]; s16x8 s; bf16x8 v; };

__device__ __forceinline__ unsigned short f2bf(float f) {
  unsigned int u = __builtin_bit_cast(unsigned int, f);
  u += 0x7fffu + ((u >> 16) & 1u);
  return (unsigned short)(u >> 16);
}

__device__ __forceinline__ unsigned int cvt_pk_bf16(float a, float b) {
  unsigned int r;
  asm("v_cvt_pk_bf16_f32 %0, %1, %2" : "=v"(r) : "v"(a), "v"(b));
  return r;  // low16 = bf16(a), high16 = bf16(b)
}

// ---------------- k_pre: all converts + conv-weight repack + conf + gather ----------------

__global__ __launch_bounds__(256) void k_pre(const float* __restrict__ q_w,
                                             const float* __restrict__ kv_w,
                                             const float* __restrict__ proj_w,
                                             const float* __restrict__ sr_w,
                                             const float* __restrict__ token_score,
                                             const int* __restrict__ idx_token,
                                             const float* __restrict__ kv_x,
                                             unsigned short* __restrict__ q_wb,
                                             unsigned short* __restrict__ kv_wb,
                                             unsigned short* __restrict__ p_wb,
                                             unsigned short* __restrict__ w4t,
                                             float* __restrict__ conf,
                                             unsigned short* __restrict__ x4) {
  int bid = blockIdx.x, t = threadIdx.x;
  if (bid < 256) { int i = bid * 256 + t; q_wb[i] = f2bf(q_w[i]); return; }
  if (bid < 768) { int i = (bid - 256) * 256 + t; kv_wb[i] = f2bf(kv_w[i]); return; }
  if (bid < 1024) { int i = (bid - 768) * 256 + t; p_wb[i] = f2bf(proj_w[i]); return; }
  if (bid < 2048) {
    // w4t[co][k], k = (dh*2+dw)*256 + ci ; from sr_w[co][ci][dh][dw]
    int idx = (bid - 1024) * 256 + t;
    int co = idx >> 10, k = idx & 1023;
    int slot = k >> 8, ci = k & 255;
    int dh = slot >> 1, dw = slot & 1;
    w4t[idx] = f2bf(sr_w[((co * 256 + ci) * 2 + dh) * 2 + dw]);
    return;
  }
  if (bid < 2080) {
    // conf[b][m] = log2e * mean_{2x2}(token_score gathered) / 1.000001
    int i = (bid - 2048) * 256 + t;  // B*1024 = 8192
    int b = i >> 10, m = i & 1023;
    int h = m >> 5, w = m & 31;
    float s = 0.f;
#pragma unroll
    for (int dh = 0; dh < 2; ++dh)
#pragma unroll
      for (int dw = 0; dw < 2; ++dw) {
        int j = (2 * h + dh) * 64 + (2 * w + dw);
        s += token_score[b * 2048 + idx_token[b * 4096 + j]];
      }
    conf[i] = s * 0.25f * (1.0f / 1.000001f) * LOG2E;
    return;
  }
  // gather: x4 rearranged for conv-as-GEMM; 4 tokens/block, f32x4 vectorized
  int gi = (bid - 2080) * 4 + (t >> 6);  // 0..32767
  int c4i = t & 63;
  int b = gi >> 12, i = gi & 4095;
  int tok = idx_token[gi];
  int y = i >> 6, x = i & 63;
  int row = ((y >> 1) << 5) + (x >> 1);
  int slot = ((y & 1) << 1) + (x & 1);
  const float inv1 = 1.0f / 1.000001f;
  f32x4 v = *(const f32x4*)(kv_x + (size_t)(b * 2048 + tok) * 256 + c4i * 4);
  u32x2 w;
  w.x = cvt_pk_bf16(v[0] * inv1, v[1] * inv1);
  w.y = cvt_pk_bf16(v[2] * inv1, v[3] * inv1);
  *(u32x2*)(x4 + (size_t)((b * 1024 + row) * 4 + slot) * 256 + c4i * 4) = w;
}

// ---------------- k_qc: fused q-projection (bid<512) + conv+LN (bid>=512), 32 rows/block ----------------

__global__ __launch_bounds__(256) void k_qc(const float* __restrict__ q_x,
                                            const unsigned short* __restrict__ q_wb,
                                            unsigned short* __restrict__ q_s,
                                            const unsigned short* __restrict__ x4,
                                            const unsigned short* __restrict__ w4t,
                                            const float* __restrict__ sr_b,
                                            const float* __restrict__ ln_w,
                                            const float* __restrict__ ln_b,
                                            unsigned short* __restrict__ kv_ln) {
  __shared__ float srow[32][260];
  int tid = threadIdx.x;
  int wid = tid >> 6, lane = tid & 63, lg = lane >> 4, lc = lane & 15;
  int bid = blockIdx.x;

  if (bid < 512) {
    // ---- q projection: 32 rows, K=256 ----
    int rowbase = bid * 32;
    f32x4 acc[2][4] = {};
    const float* ap0 = q_x + (size_t)(rowbase + lc) * 256 + lg * 8;
    const float* ap1 = ap0 + 16 * 256;
#pragma unroll
    for (int kc = 0; kc < 8; ++kc) {
      f32x4 a00 = *(const f32x4*)(ap0 + kc * 32);
      f32x4 a01 = *(const f32x4*)(ap0 + kc * 32 + 4);
      f32x4 a10 = *(const f32x4*)(ap1 + kc * 32);
      f32x4 a11 = *(const f32x4*)(ap1 + kc * 32 + 4);
      PKU a0, a1;
      a0.u[0] = cvt_pk_bf16(a00[0], a00[1]);
      a0.u[1] = cvt_pk_bf16(a00[2], a00[3]);
      a0.u[2] = cvt_pk_bf16(a01[0], a01[1]);
      a0.u[3] = cvt_pk_bf16(a01[2], a01[3]);
      a1.u[0] = cvt_pk_bf16(a10[0], a10[1]);
      a1.u[1] = cvt_pk_bf16(a10[2], a10[3]);
      a1.u[2] = cvt_pk_bf16(a11[0], a11[1]);
      a1.u[3] = cvt_pk_bf16(a11[2], a11[3]);
#pragma unroll
      for (int t = 0; t < 4; ++t) {
        ABF bb; bb.s = *(const s16x8*)(q_wb + (size_t)(wid * 64 + t * 16 + lc) * 256 + kc * 32 + lg * 8);
        acc[0][t] = __builtin_amdgcn_mfma_f32_16x16x32_bf16(a0.v, bb.v, acc[0][t], 0, 0, 0);
        acc[1][t] = __builtin_amdgcn_mfma_f32_16x16x32_bf16(a1.v, bb.v, acc[1][t], 0, 0, 0);
      }
    }
    const float qs = 0.17677669529663687f * LOG2E;
#pragma unroll
    for (int s = 0; s < 2; ++s)
#pragma unroll
      for (int t = 0; t < 4; ++t) {
        int col = wid * 64 + t * 16 + lc;
        int h = col >> 5, d = col & 31;
#pragma unroll
        for (int r = 0; r < 4; ++r) {
          int row = rowbase + s * 16 + lg * 4 + r;
          int b = row >> 11, n = row & 2047;
          q_s[(size_t)((b * 8 + h) * 2048 + n) * 32 + d] = f2bf(acc[s][t][r] * qs);
        }
      }
    return;
  }

  // ---- conv-as-GEMM + LayerNorm: 32 rows, K=1024 ----
  int rowbase = (bid - 512) * 32;
  f32x4 acc[2][4] = {};
  const unsigned short* ap0 = x4 + (size_t)(rowbase + lc) * 1024 + lg * 8;
  const unsigned short* ap1 = ap0 + 16 * 1024;
  for (int kc = 0; kc < 32; ++kc) {
    ABF a0, a1;
    a0.s = *(const s16x8*)(ap0 + kc * 32);
    a1.s = *(const s16x8*)(ap1 + kc * 32);
#pragma unroll
    for (int t = 0; t < 4; ++t) {
      ABF bb; bb.s = *(const s16x8*)(w4t + (size_t)(wid * 64 + t * 16 + lc) * 1024 + kc * 32 + lg * 8);
      acc[0][t] = __builtin_amdgcn_mfma_f32_16x16x32_bf16(a0.v, bb.v, acc[0][t], 0, 0, 0);
      acc[1][t] = __builtin_amdgcn_mfma_f32_16x16x32_bf16(a1.v, bb.v, acc[1][t], 0, 0, 0);
    }
  }
#pragma unroll
  for (int s = 0; s < 2; ++s)
#pragma unroll
    for (int t = 0; t < 4; ++t) {
      int col = wid * 64 + t * 16 + lc;
      float bias = sr_b[col];
#pragma unroll
      for (int r = 0; r < 4; ++r) srow[s * 16 + lg * 4 + r][col] = acc[s][t][r] + bias;
    }
  __syncthreads();
#pragma unroll
  for (int s = 0; s < 2; ++s) {
    int r = s * 16 + (tid >> 4), c16 = tid & 15;
    float vals[16];
    float sm = 0.f, ss = 0.f;
#pragma unroll
    for (int i = 0; i < 16; ++i) {
      float v = srow[r][c16 * 16 + i];
      vals[i] = v; sm += v; ss += v * v;
    }
#pragma unroll
    for (int m = 1; m < 16; m <<= 1) {
      sm += __shfl_xor(sm, m, 64);
      ss += __shfl_xor(ss, m, 64);
    }
    float mu = sm * (1.0f / 256.0f);
    float var = ss * (1.0f / 256.0f) - mu * mu;
    float rstd = rsqrtf(var + 1e-5f);
    s16x8 o0, o1;
#pragma unroll
    for (int i = 0; i < 8; ++i) {
      int c = c16 * 16 + i;
      o0[i] = (short)f2bf((vals[i] - mu) * rstd * ln_w[c] + ln_b[c]);
    }
#pragma unroll
    for (int i = 0; i < 8; ++i) {
      int c = c16 * 16 + 8 + i;
      o1[i] = (short)f2bf((vals[8 + i] - mu) * rstd * ln_w[c] + ln_b[c]);
    }
    *(s16x8*)(kv_ln + (size_t)(rowbase + r) * 256 + c16 * 16) = o0;
    *(s16x8*)(kv_ln + (size_t)(rowbase + r) * 256 + c16 * 16 + 8) = o1;
  }
}

// ---------------- kv projection (8192x512, K=256), 32 rows/block ----------------

__global__ __launch_bounds__(256) void k_kvproj(const unsigned short* __restrict__ kv_ln,
                                                const unsigned short* __restrict__ wb,
                                                unsigned short* __restrict__ kmat,
                                                unsigned short* __restrict__ vt) {
  int tid = threadIdx.x;
  int wid = tid >> 6, lane = tid & 63, lg = lane >> 4, lc = lane & 15;
  int rowbase = blockIdx.x * 32;
  f32x4 acc[2][8] = {};
  const unsigned short* ap0 = kv_ln + (size_t)(rowbase + lc) * 256 + lg * 8;
  const unsigned short* ap1 = ap0 + 16 * 256;
#pragma unroll
  for (int kc = 0; kc < 8; ++kc) {
    ABF a0, a1;
    a0.s = *(const s16x8*)(ap0 + kc * 32);
    a1.s = *(const s16x8*)(ap1 + kc * 32);
#pragma unroll
    for (int t = 0; t < 8; ++t) {
      ABF bb; bb.s = *(const s16x8*)(wb + (size_t)(wid * 128 + t * 16 + lc) * 256 + kc * 32 + lg * 8);
      acc[0][t] = __builtin_amdgcn_mfma_f32_16x16x32_bf16(a0.v, bb.v, acc[0][t], 0, 0, 0);
      acc[1][t] = __builtin_amdgcn_mfma_f32_16x16x32_bf16(a1.v, bb.v, acc[1][t], 0, 0, 0);
    }
  }
#pragma unroll
  for (int s = 0; s < 2; ++s)
#pragma unroll
    for (int t = 0; t < 8; ++t) {
      int j = wid * 128 + t * 16 + lc;
      int sflag = j >> 8, h = (j >> 5) & 7, d = j & 31;
#pragma unroll
      for (int r = 0; r < 4; ++r) {
        int row = rowbase + s * 16 + lg * 4 + r;
        int b = row >> 10, m = row & 1023;
        unsigned short v = f2bf(acc[s][t][r]);
        if (sflag == 0) kmat[(size_t)((b * 8 + h) * 1024 + m) * 32 + d] = v;
        else            vt[(size_t)((b * 8 + h) * 32 + d) * 1024 + m] = v;
      }
    }
}

// ---------------- flash attention: LDS-staged K/V shared by 4 waves, double-buffered ----------------
// grid 1024 blocks (XCD-swizzled), 4 waves x 32 q-rows each. Max-free log2 softmax.
__global__ __launch_bounds__(256, 4) void k_attn(const unsigned short* __restrict__ q_s,
                                                 const unsigned short* __restrict__ kmat,
                                                 const unsigned short* __restrict__ vt,
                                                 const float* __restrict__ conf,
                                                 unsigned short* __restrict__ xat) {
  __shared__ __align__(16) unsigned short Kl[2][2048];  // [64 rows][32 d], chunk^(row&3) swizzle
  __shared__ __align__(16) unsigned short Vl[2][2048];  // [32 d][64 k],   chunk^(d&7)  swizzle
  __shared__ __align__(16) float Cf[2][64];
  __shared__ __align__(16) unsigned short p_lds[8192];  // [4 wid][2 g][16 q][64 k]

  int tid = threadIdx.x;
  int wid = tid >> 6, lane = tid & 63, lg = lane >> 4, lc = lane & 15;
  // XCD swizzle: 8 heads per XCD, all 16 q-tiles of a head on the same XCD
  int bid = blockIdx.x;
  int xcd = bid & 7, slot = bid >> 3;
  int bh = xcd * 8 + (slot >> 4);
  int qt = slot & 15;
  int b = bh >> 3, h = bh & 7;
  int qbase = qt * 128 + wid * 32;

  ABF qf[2];
  qf[0].s = *(const s16x8*)(q_s + (size_t)(bh * 2048 + qbase + lc) * 32 + lg * 8);
  qf[1].s = *(const s16x8*)(q_s + (size_t)(bh * 2048 + qbase + 16 + lc) * 32 + lg * 8);

  ABF ones;
#pragma unroll
  for (int i = 0; i < 8; ++i) ones.s[i] = (short)0x3F80;  // bf16 1.0

  f32x4 oacc[2][2] = {};
  f32x4 lacc[2] = {};

  // ---- staging addressing (per thread) ----
  int krow = tid >> 2, kch = tid & 3;
  const unsigned short* kgp = kmat + (size_t)bh * 32768 + krow * 32 + kch * 8;
  int kdst = krow * 32 + ((kch ^ (krow & 3)) * 8);
  int vd = tid >> 3, vch = tid & 7;
  const unsigned short* vgp = vt + (size_t)bh * 32768 + vd * 1024 + vch * 8;
  int vdst = vd * 64 + ((vch ^ (vd & 7)) * 8);
  const float* cgp = conf + b * 1024 + (tid & 15) * 4;

  // ---- compute-side LDS offsets (shorts/floats) ----
  int kf_off[4];
#pragma unroll
  for (int t = 0; t < 4; ++t) kf_off[t] = (t * 16 + lc) * 32 + ((lg ^ (lc & 3)) * 8);
  int vb_off[2][2];
#pragma unroll
  for (int c = 0; c < 2; ++c)
#pragma unroll
    for (int dh = 0; dh < 2; ++dh)
      vb_off[c][dh] = (dh * 16 + lc) * 64 + (((4 * c + lg) ^ (lc & 7)) * 8);
  int c4_off = lg * 4;

  // p_lds swizzled offsets: row = lc (128B), slot' = slot ^ (lc&7)
  unsigned short* ldsrow = p_lds + (wid * 2 * 16 + lc) * 64;
  int sw = lc & 7;
  int w_off[4], r_off[2];
#pragma unroll
  for (int t = 0; t < 4; ++t)
    w_off[t] = (((2 * t + (lg >> 1)) ^ sw) << 3) + ((lg & 1) << 2);
#pragma unroll
  for (int p = 0; p < 2; ++p)
    r_off[p] = ((p * 4 + lg) ^ sw) << 3;

  // ---- stage tile 0 ----
  s16x8 pk = *(const s16x8*)(kgp);
  s16x8 pv = *(const s16x8*)(vgp);
  f32x4 pc;
  if (tid < 16) pc = *(const f32x4*)(cgp);
  *(s16x8*)(&Kl[0][kdst]) = pk;
  *(s16x8*)(&Vl[0][vdst]) = pv;
  if (tid < 16) *(f32x4*)(&Cf[0][tid * 4]) = pc;
  __syncthreads();

#pragma unroll 2
  for (int it = 0; it < 16; ++it) {
    const int buf = it & 1;
    if (it < 15) {  // prefetch next tile into registers (latency hides under compute)
      pk = *(const s16x8*)(kgp + (it + 1) * 2048);
      pv = *(const s16x8*)(vgp + (it + 1) * 64);
      if (tid < 16) pc = *(const f32x4*)(cgp + (it + 1) * 64);
    }
    // ---- compute on buf ----
    ABF kf[4]; f32x4 c4[4];
#pragma unroll
    for (int t = 0; t < 4; ++t) {
      kf[t].s = *(const s16x8*)(&Kl[buf][kf_off[t]]);
      c4[t] = *(const f32x4*)(&Cf[buf][t * 16 + c4_off]);
    }
    ABF vb[2][2];
#pragma unroll
    for (int c = 0; c < 2; ++c)
#pragma unroll
      for (int dh = 0; dh < 2; ++dh)
        vb[c][dh].s = *(const s16x8*)(&Vl[buf][vb_off[c][dh]]);

    // swapped QK^T: lane holds q=lc, k rows
#pragma unroll
    for (int g = 0; g < 2; ++g) {
      unsigned short* lrow = ldsrow + g * 1024;
#pragma unroll
      for (int t = 0; t < 4; ++t) {
        f32x4 st = __builtin_amdgcn_mfma_f32_16x16x32_bf16(kf[t].v, qf[g].v, c4[t], 0, 0, 0);
        f32x4 pt;
        pt[0] = __builtin_amdgcn_exp2f(st[0]);
        pt[1] = __builtin_amdgcn_exp2f(st[1]);
        pt[2] = __builtin_amdgcn_exp2f(st[2]);
        pt[3] = __builtin_amdgcn_exp2f(st[3]);
        u32x2 w;
        w.x = cvt_pk_bf16(pt[0], pt[1]);
        w.y = cvt_pk_bf16(pt[2], pt[3]);
        *(u32x2*)(lrow + w_off[t]) = w;
      }
    }
    // PV + row-sum via ones-MFMA
#pragma unroll
    for (int g = 0; g < 2; ++g) {
      unsigned short* lrow = ldsrow + g * 1024;
      ABF pa0, pa1;
      pa0.s = *(const s16x8*)(lrow + r_off[0]);
      pa1.s = *(const s16x8*)(lrow + r_off[1]);
      oacc[g][0] = __builtin_amdgcn_mfma_f32_16x16x32_bf16(pa0.v, vb[0][0].v, oacc[g][0], 0, 0, 0);
      oacc[g][1] = __builtin_amdgcn_mfma_f32_16x16x32_bf16(pa0.v, vb[0][1].v, oacc[g][1], 0, 0, 0);
      lacc[g]    = __builtin_amdgcn_mfma_f32_16x16x32_bf16(pa0.v, ones.v,     lacc[g],    0, 0, 0);
      oacc[g][0] = __builtin_amdgcn_mfma_f32_16x16x32_bf16(pa1.v, vb[1][0].v, oacc[g][0], 0, 0, 0);
      oacc[g][1] = __builtin_amdgcn_mfma_f32_16x16x32_bf16(pa1.v, vb[1][1].v, oacc[g][1], 0, 0, 0);
      lacc[g]    = __builtin_amdgcn_mfma_f32_16x16x32_bf16(pa1.v, ones.v,     lacc[g],    0, 0, 0);
    }
    // ---- write prefetched tile to the other buffer ----
    if (it < 15) {
      *(s16x8*)(&Kl[buf ^ 1][kdst]) = pk;
      *(s16x8*)(&Vl[buf ^ 1][vdst]) = pv;
      if (tid < 16) *(f32x4*)(&Cf[buf ^ 1][tid * 4]) = pc;
    }
    __syncthreads();
  }

#pragma unroll
  for (int g = 0; g < 2; ++g) {
#pragma unroll
    for (int r = 0; r < 4; ++r) {
      float inv = 1.0f / lacc[g][r];
      int q = qbase + g * 16 + lg * 4 + r;
      xat[(size_t)(b * 2048 + q) * 256 + h * 32 + lc] = f2bf(oacc[g][0][r] * inv);
      xat[(size_t)(b * 2048 + q) * 256 + h * 32 + 16 + lc] = f2bf(oacc[g][1][r] * inv);
    }
  }
}

// ---------------- final projection (16384x256, K=256) + bias -> f32, 32 rows/block ----------------

__global__ __launch_bounds__(256) void k_proj(const unsigned short* __restrict__ xat,
                                              const unsigned short* __restrict__ wb,
                                              const float* __restrict__ pb,
                                              float* __restrict__ out) {
  int tid = threadIdx.x;
  int wid = tid >> 6, lane = tid & 63, lg = lane >> 4, lc = lane & 15;
  int rowbase = blockIdx.x * 32;
  f32x4 acc[2][4] = {};
  const unsigned short* ap0 = xat + (size_t)(rowbase + lc) * 256 + lg * 8;
  const unsigned short* ap1 = ap0 + 16 * 256;
#pragma unroll
  for (int kc = 0; kc < 8; ++kc) {
    ABF a0, a1;
    a0.s = *(const s16x8*)(ap0 + kc * 32);
    a1.s = *(const s16x8*)(ap1 + kc * 32);
#pragma unroll
    for (int t = 0; t < 4; ++t) {
      ABF bb; bb.s = *(const s16x8*)(wb + (size_t)(wid * 64 + t * 16 + lc) * 256 + kc * 32 + lg * 8);
      acc[0][t] = __builtin_amdgcn_mfma_f32_16x16x32_bf16(a0.v, bb.v, acc[0][t], 0, 0, 0);
      acc[1][t] = __builtin_amdgcn_mfma_f32_16x16x32_bf16(a1.v, bb.v, acc[1][t], 0, 0, 0);
    }
  }
#pragma unroll
  for (int s = 0; s < 2; ++s)
#pragma unroll
    for (int t = 0; t < 4; ++t) {
      int col = wid * 64 + t * 16 + lc;
      float bias = pb[col];
#pragma unroll
      for (int r = 0; r < 4; ++r) {
        int row = rowbase + s * 16 + lg * 4 + r;
        out[(size_t)row * 256 + col] = acc[s][t][r] + bias;
      }
    }
}

// ---------------- launch ----------------

extern "C" void kernel_launch(void* const* d_in, const int* in_sizes, int n_in,
                              void* d_out, int out_size, void* d_ws, size_t ws_size,
                              hipStream_t stream) {
  (void)in_sizes; (void)n_in; (void)out_size; (void)ws_size;
  const float* q_x         = (const float*)d_in[0];
  const float* kv_x        = (const float*)d_in[1];
  const float* token_score = (const float*)d_in[2];
  const int*   idx_token   = (const int*)d_in[3];
  const float* q_w         = (const float*)d_in[4];
  const float* kv_w        = (const float*)d_in[5];
  const float* proj_w      = (const float*)d_in[6];
  const float* proj_b      = (const float*)d_in[7];
  const float* sr_w        = (const float*)d_in[8];
  const float* sr_b        = (const float*)d_in[9];
  const float* ln_w        = (const float*)d_in[10];
  const float* ln_b        = (const float*)d_in[11];
  float* out = (float*)d_out;

  char* ws = (char*)d_ws;
  unsigned short* q_s   = (unsigned short*)(ws + 0);          // 64*2048*32  bf16 = 8 MB
  unsigned short* x4    = (unsigned short*)(ws + 8388608);    // 8192*1024   bf16 = 16 MB
  unsigned short* xat   = (unsigned short*)(ws + 8388608);    // aliases x4 (dead by attn time)
  unsigned short* w4t   = (unsigned short*)(ws + 25165824);   // 256*1024    bf16
  unsigned short* kv_ln = (unsigned short*)(ws + 25690112);   // 8192*256    bf16
  unsigned short* kmat  = (unsigned short*)(ws + 29884416);   // 64*1024*32  bf16
  unsigned short* vt    = (unsigned short*)(ws + 34078720);   // 64*32*1024  bf16
  float*          confp = (float*)(ws + 38273024);            // 8*1024      f32
  unsigned short* q_wb  = (unsigned short*)(ws + 46694400);   // 256*256     bf16
  unsigned short* kv_wb = (unsigned short*)(ws + 46825472);   // 512*256     bf16
  unsigned short* p_wb  = (unsigned short*)(ws + 47087616);   // 256*256     bf16

  k_pre<<<dim3(10272), dim3(256), 0, stream>>>(q_w, kv_w, proj_w, sr_w, token_score, idx_token,
                                               kv_x, q_wb, kv_wb, p_wb, w4t, confp, x4);
  k_qc<<<dim3(768), dim3(256), 0, stream>>>(q_x, q_wb, q_s, x4, w4t, sr_b, ln_w, ln_b, kv_ln);
  k_kvproj<<<dim3(256), dim3(256), 0, stream>>>(kv_ln, kv_wb, kmat, vt);
  k_attn<<<dim3(1024), dim3(256), 0, stream>>>(q_s, kmat, vt, confp, xat);
  k_proj<<<dim3(512), dim3(256), 0, stream>>>(xat, p_wb, proj_b, out);
}